// Round 3
// baseline (2977.719 us; speedup 1.0000x reference)
//
#include <hip/hip_runtime.h>
#include <math.h>

#define NE 64
#define NTOK 16384
#define DD 4096
#define TOPK 2
#define NWAVE 16              // waves per block = K-slices
#define BLOCK 1024
#define KRANGE (DD / NWAVE)   // 256 k per wave
#define KC 32                 // k per staged chunk (128 B per row = full line)
#define NCH (KRANGE / KC)     // 8 chunks
#define LGSTR 68              // logit tile row stride (dwords, 16B-aligned)

__global__ __launch_bounds__(BLOCK, 4) void router_kernel(
    const float* __restrict__ x, const float* __restrict__ gw,
    float* __restrict__ out, float* __restrict__ ws) {
  // 16 waves x 64 expert-rows x 32 k = 128 KB; later aliased as logit tile +
  // loss-partial scratch (compute is finished before aliasing, barrier-guarded).
  __shared__ __align__(16) float smem[NWAVE * NE * KC];
  float* lg = smem;  // [64 tok][LGSTR]

  const int tid = threadIdx.x;
  const int lane = tid & 63;
  const int wid = __builtin_amdgcn_readfirstlane(tid >> 6);
  const int g = lane >> 4;   // expert group: experts g*16 .. g*16+15
  const int s = lane & 15;   // token slot: tokens s + 16*j, j = 0..3
  const int g2 = g * 2;
  const int tok0 = blockIdx.x * 64;

  float* wtw = &smem[wid * (NE * KC)];           // this wave's weight chunk
  const float* wg = gw + (size_t)lane * DD + wid * KRANGE;  // staging row = lane
  const int fw = (lane & 7) ^ (lane >> 3);       // write swizzle

  const float* xb0 = x + (size_t)(tok0 + s) * DD + wid * KRANGE;
  const float* xb1 = xb0 + (size_t)16 * DD;
  const float* xb2 = xb0 + (size_t)32 * DD;
  const float* xb3 = xb0 + (size_t)48 * DD;

  // per-expert swizzled read offsets (dwords); bits disjoint -> XOR with q*4 walks quads
  int co[16];
#pragma unroll
  for (int e = 0; e < 16; ++e) {
    const int row = g * 16 + e;
    const int fr = (e & 7) ^ (g2 + (e >> 3));    // distinct across g -> conflict-free
    co[e] = (row << 5) + (fr << 2);
  }

  float acc[4][16];
#pragma unroll
  for (int j = 0; j < 4; ++j)
#pragma unroll
    for (int e = 0; e < 16; ++e) acc[j][e] = 0.f;

  // stage chunk 0 (per-wave, no barrier needed)
#pragma unroll
  for (int q = 0; q < 8; ++q) {
    float4 v = *(const float4*)(wg + q * 4);
    *(float4*)&wtw[(lane << 5) + ((q ^ fw) << 2)] = v;
  }

#pragma unroll 1
  for (int c = 0; c < NCH; ++c) {
    const int kc = c * KC;
#pragma unroll
    for (int q = 0; q < 8; ++q) {
      const int ko = kc + q * 4;
      float4 x0 = *(const float4*)(xb0 + ko);
      float4 x1 = *(const float4*)(xb1 + ko);
      float4 x2 = *(const float4*)(xb2 + ko);
      float4 x3 = *(const float4*)(xb3 + ko);
#pragma unroll
      for (int e = 0; e < 16; ++e) {
        const float4 w = *(const float4*)&wtw[co[e] ^ (q << 2)];
        acc[0][e] = fmaf(x0.x, w.x, acc[0][e]);
        acc[0][e] = fmaf(x0.y, w.y, acc[0][e]);
        acc[0][e] = fmaf(x0.z, w.z, acc[0][e]);
        acc[0][e] = fmaf(x0.w, w.w, acc[0][e]);
        acc[1][e] = fmaf(x1.x, w.x, acc[1][e]);
        acc[1][e] = fmaf(x1.y, w.y, acc[1][e]);
        acc[1][e] = fmaf(x1.z, w.z, acc[1][e]);
        acc[1][e] = fmaf(x1.w, w.w, acc[1][e]);
        acc[2][e] = fmaf(x2.x, w.x, acc[2][e]);
        acc[2][e] = fmaf(x2.y, w.y, acc[2][e]);
        acc[2][e] = fmaf(x2.z, w.z, acc[2][e]);
        acc[2][e] = fmaf(x2.w, w.w, acc[2][e]);
        acc[3][e] = fmaf(x3.x, w.x, acc[3][e]);
        acc[3][e] = fmaf(x3.y, w.y, acc[3][e]);
        acc[3][e] = fmaf(x3.z, w.z, acc[3][e]);
        acc[3][e] = fmaf(x3.w, w.w, acc[3][e]);
      }
    }
    if (c + 1 < NCH) {  // stage next chunk; same-wave DS ordering makes this safe
#pragma unroll
      for (int q = 0; q < 8; ++q) {
        float4 v = *(const float4*)(wg + (c + 1) * KC + q * 4);
        *(float4*)&wtw[(lane << 5) + ((q ^ fw) << 2)] = v;
      }
    }
  }

  __syncthreads();  // all compute done before smem is reused as logit tile

  // deterministic 16-phase K-slice reduction into lg[tok][e]
#pragma unroll 1
  for (int w = 0; w < NWAVE; ++w) {
    if (wid == w) {
#pragma unroll
      for (int j = 0; j < 4; ++j) {
        float* row = &lg[(s + 16 * j) * LGSTR + g * 16];
#pragma unroll
        for (int e4 = 0; e4 < 4; ++e4) {
          float4 v;
          v.x = acc[j][e4 * 4 + 0];
          v.y = acc[j][e4 * 4 + 1];
          v.z = acc[j][e4 * 4 + 2];
          v.w = acc[j][e4 * 4 + 3];
          if (w != 0) {
            float4 o = *(const float4*)&row[e4 * 4];
            v.x += o.x; v.y += o.y; v.z += o.z; v.w += o.w;
          }
          *(float4*)&row[e4 * 4] = v;
        }
      }
    }
    __syncthreads();
  }

  // epilogue: wave wid handles tokens wid*4 .. wid*4+3; lane == expert
  float psum_local = 0.f, cnt_local = 0.f;
  float* out_v = out;                // (NTOK, 2) top-k vals
  float* out_i = out + NTOK * TOPK;  // (NTOK, 2) top-k idx as float
#pragma unroll 1
  for (int ii = 0; ii < 4; ++ii) {
    const int t = wid * 4 + ii;
    float v = lg[t * LGSTR + lane];
    float m = v;
#pragma unroll
    for (int sh = 32; sh > 0; sh >>= 1) m = fmaxf(m, __shfl_xor(m, sh, 64));
    float ex = expf(v - m);
    float ssum = ex;
#pragma unroll
    for (int sh = 32; sh > 0; sh >>= 1) ssum += __shfl_xor(ssum, sh, 64);
    float p = ex / ssum;
    psum_local += p;

    float v1 = p; int i1 = lane;  // top-1, ties -> lowest index
#pragma unroll
    for (int sh = 32; sh > 0; sh >>= 1) {
      float ov = __shfl_xor(v1, sh, 64);
      int oi = __shfl_xor(i1, sh, 64);
      if (ov > v1 || (ov == v1 && oi < i1)) { v1 = ov; i1 = oi; }
    }
    float v2 = (lane == i1) ? -INFINITY : p; int i2 = lane;  // top-2
#pragma unroll
    for (int sh = 32; sh > 0; sh >>= 1) {
      float ov = __shfl_xor(v2, sh, 64);
      int oi = __shfl_xor(i2, sh, 64);
      if (ov > v2 || (ov == v2 && oi < i2)) { v2 = ov; i2 = oi; }
    }
    cnt_local += (lane == i1 ? 1.f : 0.f) + (lane == i2 ? 1.f : 0.f);
    if (lane == 0) {
      const int tg = tok0 + t;
      out_v[tg * 2 + 0] = v1;
      out_v[tg * 2 + 1] = v2;
      out_i[tg * 2 + 0] = (float)i1;
      out_i[tg * 2 + 1] = (float)i2;
    }
  }

  // block-level reduction of loss partials -> 2 atomics per lane per block
  smem[4352 + tid] = psum_local;          // lg uses dwords [0, 4348)
  smem[4352 + BLOCK + tid] = cnt_local;
  __syncthreads();
  if (wid == 0) {
    float ps = 0.f, cs = 0.f;
#pragma unroll
    for (int w = 0; w < NWAVE; ++w) {
      ps += smem[4352 + w * 64 + lane];
      cs += smem[4352 + BLOCK + w * 64 + lane];
    }
    atomicAdd(ws + lane, cs);
    atomicAdd(ws + NE + lane, ps);
  }
}

__global__ void loss_kernel(const float* __restrict__ ws,
                            float* __restrict__ out) {
  const int lane = threadIdx.x & 63;
  float f = ws[lane] * (1.f / (float)(NTOK * TOPK));
  float p = ws[NE + lane] * (1.f / (float)NTOK);
  float v = f * p;  // loss = E * mean_i(f_i p_i) = sum_i f_i p_i
#pragma unroll
  for (int sh = 32; sh > 0; sh >>= 1) v += __shfl_xor(v, sh, 64);
  if (lane == 0) out[NTOK * TOPK * 2] = v;
}

extern "C" void kernel_launch(void* const* d_in, const int* in_sizes, int n_in,
                              void* d_out, int out_size, void* d_ws,
                              size_t ws_size, hipStream_t stream) {
  const float* x = (const float*)d_in[0];
  const float* gw = (const float*)d_in[1];
  float* out = (float*)d_out;
  float* ws = (float*)d_ws;

  hipMemsetAsync(d_ws, 0, 2 * NE * sizeof(float), stream);
  router_kernel<<<NTOK / 64, BLOCK, 0, stream>>>(x, gw, out, ws);
  loss_kernel<<<1, 64, 0, stream>>>(ws, out);
}

// Round 4
// 2852.165 us; speedup vs baseline: 1.0440x; 1.0440x over previous
//
#include <hip/hip_runtime.h>
#include <math.h>

#define NE 64
#define NTOK 16384
#define DD 4096
#define TOPK 2
#define BLOCK 512             // 8 waves = 2 token-groups x 4 K-quarters
#define TOKPB 64
#define KQn 4
#define KRANGE (DD / KQn)     // 1024 k per quarter
#define KC 32                 // k per chunk
#define NCH (KRANGE / KC)     // 32 chunks
#define WBUF 2048             // dwords per weight buffer (64 exp x 32 k)
#define LGSTR 68              // logit row stride (dwords, 16B aligned)
#define LGKQ (64 * LGSTR)     // 4352 dwords per kq logit plane
#define SMEM_DW (KQn * LGKQ)  // 17408 dwords = 69.6 KB (>= 8*WBUF = 16384)

__global__ __launch_bounds__(BLOCK, 4) void router_kernel(
    const float* __restrict__ x, const float* __restrict__ gw,
    float* __restrict__ out, float* __restrict__ ws) {
  __shared__ __align__(16) float smem[SMEM_DW];

  const int tid = threadIdx.x;
  const int lane = tid & 63;
  const int wid = __builtin_amdgcn_readfirstlane(tid >> 6);
  const int tg = wid & 1;   // token group (32 tokens)
  const int kq = wid >> 1;  // K quarter
  const int g = lane >> 3;  // expert group: experts g*8..g*8+7
  const int s = lane & 7;   // token slot: tokens s + 8*t
  const int tok0 = blockIdx.x * TOKPB;

  // per-lane x row pointers (4 tokens, stride 8)
  const float* xp0 = x + (size_t)(tok0 + tg * 32 + s) * DD + kq * KRANGE;
  const float* xp1 = xp0 + (size_t)8 * DD;
  const float* xp2 = xp0 + (size_t)16 * DD;
  const float* xp3 = xp0 + (size_t)24 * DD;

  // weight staging: the kq-pair (128 lanes) stages 64exp x 32k per chunk
  const int l2 = tid & 127;
  const int eh = l2 >> 3;  // 0..15
  const int jq = l2 & 7;   // quad column
  const float* gws = gw + (size_t)eh * DD + kq * KRANGE + jq * 4;
  float* wb0 = &smem[(kq * 2 + 0) * WBUF];
  float* wb1 = &smem[(kq * 2 + 1) * WBUF];
  int wdst[4];
#pragma unroll
  for (int r = 0; r < 4; ++r) {
    const int e = r * 16 + eh;
    wdst[r] = e * 32 + ((jq ^ (e >> 3)) << 2);  // XOR-swizzled quad slot
  }

  float4 st[4];
  float4 xq[2][4];
  float acc[4][8];
#pragma unroll
  for (int t = 0; t < 4; ++t)
#pragma unroll
    for (int e = 0; e < 8; ++e) acc[t][e] = 0.f;

  // prologue: stage chunk 0, preload stage regs chunk 1, x quads 0..1
#pragma unroll
  for (int r = 0; r < 4; ++r) st[r] = *(const float4*)(gws + (size_t)r * 16 * DD);
#pragma unroll
  for (int r = 0; r < 4; ++r) *(float4*)&wb0[wdst[r]] = st[r];
#pragma unroll
  for (int r = 0; r < 4; ++r)
    st[r] = *(const float4*)(gws + (size_t)r * 16 * DD + KC);
#pragma unroll
  for (int pq = 0; pq < 2; ++pq) {
    xq[pq][0] = *(const float4*)(xp0 + pq * 4);
    xq[pq][1] = *(const float4*)(xp1 + pq * 4);
    xq[pq][2] = *(const float4*)(xp2 + pq * 4);
    xq[pq][3] = *(const float4*)(xp3 + pq * 4);
  }
  __syncthreads();

  const int ldsg = g * 256;  // dword base of this group's first row

#pragma unroll 1
  for (int c = 0; c < NCH; ++c) {
    const float* wbc = (c & 1) ? wb1 : wb0;
    float* wbn = (c & 1) ? wb0 : wb1;
#pragma unroll
    for (int q = 0; q < 8; ++q) {
      const int qi = c * 8 + q;
      const float* wrow = &wbc[ldsg + ((q ^ g) << 2)];
      const float4 x0 = xq[q & 1][0], x1 = xq[q & 1][1];
      const float4 x2 = xq[q & 1][2], x3 = xq[q & 1][3];
      if (qi + 2 < KRANGE / 4) {  // uniform branch: prefetch 2 quads ahead
        xq[q & 1][0] = *(const float4*)(xp0 + (qi + 2) * 4);
        xq[q & 1][1] = *(const float4*)(xp1 + (qi + 2) * 4);
        xq[q & 1][2] = *(const float4*)(xp2 + (qi + 2) * 4);
        xq[q & 1][3] = *(const float4*)(xp3 + (qi + 2) * 4);
      }
#pragma unroll
      for (int e = 0; e < 8; ++e) {
        const float4 w = *(const float4*)&wrow[e * 32];
        acc[0][e] = fmaf(x0.x, w.x, acc[0][e]);
        acc[0][e] = fmaf(x0.y, w.y, acc[0][e]);
        acc[0][e] = fmaf(x0.z, w.z, acc[0][e]);
        acc[0][e] = fmaf(x0.w, w.w, acc[0][e]);
        acc[1][e] = fmaf(x1.x, w.x, acc[1][e]);
        acc[1][e] = fmaf(x1.y, w.y, acc[1][e]);
        acc[1][e] = fmaf(x1.z, w.z, acc[1][e]);
        acc[1][e] = fmaf(x1.w, w.w, acc[1][e]);
        acc[2][e] = fmaf(x2.x, w.x, acc[2][e]);
        acc[2][e] = fmaf(x2.y, w.y, acc[2][e]);
        acc[2][e] = fmaf(x2.z, w.z, acc[2][e]);
        acc[2][e] = fmaf(x2.w, w.w, acc[2][e]);
        acc[3][e] = fmaf(x3.x, w.x, acc[3][e]);
        acc[3][e] = fmaf(x3.y, w.y, acc[3][e]);
        acc[3][e] = fmaf(x3.z, w.z, acc[3][e]);
        acc[3][e] = fmaf(x3.w, w.w, acc[3][e]);
      }
    }
    if (c + 1 < NCH) {  // write staged regs -> next buffer
#pragma unroll
      for (int r = 0; r < 4; ++r) *(float4*)&wbn[wdst[r]] = st[r];
    }
    if (c + 2 < NCH) {  // issue loads for chunk c+2 (hidden under next compute)
#pragma unroll
      for (int r = 0; r < 4; ++r)
        st[r] = *(const float4*)(gws + (size_t)r * 16 * DD + (c + 2) * KC);
    }
    __syncthreads();
  }

  // write partial logits: lgp[kq][tok_local 64][LGSTR] (aliases dead wbufs)
  {
    float* lgp = &smem[kq * LGKQ];
#pragma unroll
    for (int t = 0; t < 4; ++t) {
      float* row = &lgp[(tg * 32 + s + 8 * t) * LGSTR + g * 8];
      float4 a0, a1;
      a0.x = acc[t][0]; a0.y = acc[t][1]; a0.z = acc[t][2]; a0.w = acc[t][3];
      a1.x = acc[t][4]; a1.y = acc[t][5]; a1.z = acc[t][6]; a1.w = acc[t][7];
      *(float4*)&row[0] = a0;
      *(float4*)&row[4] = a1;
    }
  }
  __syncthreads();

  // epilogue: wave wid -> tokens wid*8..wid*8+7; lane == expert
  float psum_local = 0.f, cnt_local = 0.f;
  float* out_v = out;                // (NTOK, 2) top-k vals
  float* out_i = out + NTOK * TOPK;  // (NTOK, 2) top-k idx as float
#pragma unroll 1
  for (int ii = 0; ii < 8; ++ii) {
    const int t = wid * 8 + ii;
    float v = smem[0 * LGKQ + t * LGSTR + lane] +
              smem[1 * LGKQ + t * LGSTR + lane] +
              smem[2 * LGKQ + t * LGSTR + lane] +
              smem[3 * LGKQ + t * LGSTR + lane];
    float m = v;
#pragma unroll
    for (int sh = 32; sh > 0; sh >>= 1) m = fmaxf(m, __shfl_xor(m, sh, 64));
    float ex = expf(v - m);
    float ssum = ex;
#pragma unroll
    for (int sh = 32; sh > 0; sh >>= 1) ssum += __shfl_xor(ssum, sh, 64);
    float p = ex / ssum;
    psum_local += p;

    float v1 = p; int i1 = lane;  // top-1, ties -> lowest index
#pragma unroll
    for (int sh = 32; sh > 0; sh >>= 1) {
      float ov = __shfl_xor(v1, sh, 64);
      int oi = __shfl_xor(i1, sh, 64);
      if (ov > v1 || (ov == v1 && oi < i1)) { v1 = ov; i1 = oi; }
    }
    float v2 = (lane == i1) ? -INFINITY : p; int i2 = lane;  // top-2
#pragma unroll
    for (int sh = 32; sh > 0; sh >>= 1) {
      float ov = __shfl_xor(v2, sh, 64);
      int oi = __shfl_xor(i2, sh, 64);
      if (ov > v2 || (ov == v2 && oi < i2)) { v2 = ov; i2 = oi; }
    }
    cnt_local += (lane == i1 ? 1.f : 0.f) + (lane == i2 ? 1.f : 0.f);
    if (lane == 0) {
      const int tgl = tok0 + t;
      out_v[tgl * 2 + 0] = v1;
      out_v[tgl * 2 + 1] = v2;
      out_i[tgl * 2 + 0] = (float)i1;
      out_i[tgl * 2 + 1] = (float)i2;
    }
  }
  // loss partials: ws[0:64] = pick counts, ws[64:128] = prob sums
  atomicAdd(ws + lane, cnt_local);
  atomicAdd(ws + NE + lane, psum_local);
}

__global__ void loss_kernel(const float* __restrict__ ws,
                            float* __restrict__ out) {
  const int lane = threadIdx.x & 63;
  float f = ws[lane] * (1.f / (float)(NTOK * TOPK));
  float p = ws[NE + lane] * (1.f / (float)NTOK);
  float v = f * p;  // loss = E * mean_i(f_i p_i) = sum_i f_i p_i
#pragma unroll
  for (int sh = 32; sh > 0; sh >>= 1) v += __shfl_xor(v, sh, 64);
  if (lane == 0) out[NTOK * TOPK * 2] = v;
}

extern "C" void kernel_launch(void* const* d_in, const int* in_sizes, int n_in,
                              void* d_out, int out_size, void* d_ws,
                              size_t ws_size, hipStream_t stream) {
  const float* x = (const float*)d_in[0];
  const float* gw = (const float*)d_in[1];
  float* out = (float*)d_out;
  float* ws = (float*)d_ws;

  hipMemsetAsync(d_ws, 0, 2 * NE * sizeof(float), stream);
  router_kernel<<<NTOK / TOKPB, BLOCK, 0, stream>>>(x, gw, out, ws);
  loss_kernel<<<1, 64, 0, stream>>>(ws, out);
}

// Round 5
// 1519.261 us; speedup vs baseline: 1.9600x; 1.8773x over previous
//
#include <hip/hip_runtime.h>
#include <math.h>

#define NE 64
#define NTOK 16384
#define DD 4096
#define TOPK 2
#define BLOCK 512             // 8 waves = 2 token-groups x 4 K-quarters
#define TOKPB 64
#define KQn 4
#define KRANGE (DD / KQn)     // 1024 k per quarter
#define KC 32                 // k per chunk
#define NCH (KRANGE / KC)     // 32 chunks
#define WBUF 2048             // dwords per weight buffer (64 exp x 32 k)
#define LGSTR 68              // logit row stride (dwords, 16B aligned)
#define LGKQ (64 * LGSTR)     // 4352 dwords per kq logit plane
#define SMEM_DW (KQn * LGKQ)  // 17408 dwords = 69.6 KB (>= 8*WBUF = 16384)

// NOTE: second __launch_bounds__ arg behaves as min BLOCKS/CU here (observed:
// (512,4) -> 64-VGPR cap -> mass spills). (512,2) -> 128-VGPR cap, 2 blk/CU.
__global__ __launch_bounds__(BLOCK, 2) void router_kernel(
    const float* __restrict__ x, const float* __restrict__ gw,
    float* __restrict__ out, float* __restrict__ ws) {
  __shared__ __align__(16) float smem[SMEM_DW];

  const int tid = threadIdx.x;
  const int lane = tid & 63;
  const int wid = __builtin_amdgcn_readfirstlane(tid >> 6);
  const int tg = wid & 1;   // token group (32 tokens)
  const int kq = wid >> 1;  // K quarter
  const int g = lane >> 3;  // expert group: experts g*8..g*8+7
  const int s = lane & 7;   // token slot: tokens s + 8*t
  const int tok0 = blockIdx.x * TOKPB;

  // per-lane x row pointers (4 tokens, stride 8)
  const float* xp0 = x + (size_t)(tok0 + tg * 32 + s) * DD + kq * KRANGE;
  const float* xp1 = xp0 + (size_t)8 * DD;
  const float* xp2 = xp0 + (size_t)16 * DD;
  const float* xp3 = xp0 + (size_t)24 * DD;

  // weight staging: the kq-pair (128 lanes) stages 64exp x 32k per chunk
  const int l2 = tid & 127;
  const int eh = l2 >> 3;  // 0..15
  const int jq = l2 & 7;   // quad column
  const float* gws = gw + (size_t)eh * DD + kq * KRANGE + jq * 4;
  float* wb0 = &smem[(kq * 2 + 0) * WBUF];
  float* wb1 = &smem[(kq * 2 + 1) * WBUF];
  int wdst[4];
#pragma unroll
  for (int r = 0; r < 4; ++r) {
    const int e = r * 16 + eh;
    wdst[r] = e * 32 + ((jq ^ (e >> 3)) << 2);  // XOR-swizzled quad slot
  }

  float4 st[4];
  float4 xq[2][4];
  float acc[4][8];
#pragma unroll
  for (int t = 0; t < 4; ++t)
#pragma unroll
    for (int e = 0; e < 8; ++e) acc[t][e] = 0.f;

  // prologue: stage chunk 0, preload stage regs chunk 1, x quads 0..1
#pragma unroll
  for (int r = 0; r < 4; ++r) st[r] = *(const float4*)(gws + (size_t)r * 16 * DD);
#pragma unroll
  for (int r = 0; r < 4; ++r) *(float4*)&wb0[wdst[r]] = st[r];
#pragma unroll
  for (int r = 0; r < 4; ++r)
    st[r] = *(const float4*)(gws + (size_t)r * 16 * DD + KC);
#pragma unroll
  for (int pq = 0; pq < 2; ++pq) {
    xq[pq][0] = *(const float4*)(xp0 + pq * 4);
    xq[pq][1] = *(const float4*)(xp1 + pq * 4);
    xq[pq][2] = *(const float4*)(xp2 + pq * 4);
    xq[pq][3] = *(const float4*)(xp3 + pq * 4);
  }
  __syncthreads();

  const int ldsg = g * 256;  // dword base of this group's first row

#pragma unroll 1
  for (int c = 0; c < NCH; ++c) {
    const float* wbc = (c & 1) ? wb1 : wb0;
    float* wbn = (c & 1) ? wb0 : wb1;
#pragma unroll
    for (int q = 0; q < 8; ++q) {
      const int qi = c * 8 + q;
      const float* wrow = &wbc[ldsg + ((q ^ g) << 2)];
      const float4 x0 = xq[q & 1][0], x1 = xq[q & 1][1];
      const float4 x2 = xq[q & 1][2], x3 = xq[q & 1][3];
      if (qi + 2 < KRANGE / 4) {  // uniform branch: prefetch 2 quads ahead
        xq[q & 1][0] = *(const float4*)(xp0 + (qi + 2) * 4);
        xq[q & 1][1] = *(const float4*)(xp1 + (qi + 2) * 4);
        xq[q & 1][2] = *(const float4*)(xp2 + (qi + 2) * 4);
        xq[q & 1][3] = *(const float4*)(xp3 + (qi + 2) * 4);
      }
#pragma unroll
      for (int e = 0; e < 8; ++e) {
        const float4 w = *(const float4*)&wrow[e * 32];
        acc[0][e] = fmaf(x0.x, w.x, acc[0][e]);
        acc[0][e] = fmaf(x0.y, w.y, acc[0][e]);
        acc[0][e] = fmaf(x0.z, w.z, acc[0][e]);
        acc[0][e] = fmaf(x0.w, w.w, acc[0][e]);
        acc[1][e] = fmaf(x1.x, w.x, acc[1][e]);
        acc[1][e] = fmaf(x1.y, w.y, acc[1][e]);
        acc[1][e] = fmaf(x1.z, w.z, acc[1][e]);
        acc[1][e] = fmaf(x1.w, w.w, acc[1][e]);
        acc[2][e] = fmaf(x2.x, w.x, acc[2][e]);
        acc[2][e] = fmaf(x2.y, w.y, acc[2][e]);
        acc[2][e] = fmaf(x2.z, w.z, acc[2][e]);
        acc[2][e] = fmaf(x2.w, w.w, acc[2][e]);
        acc[3][e] = fmaf(x3.x, w.x, acc[3][e]);
        acc[3][e] = fmaf(x3.y, w.y, acc[3][e]);
        acc[3][e] = fmaf(x3.z, w.z, acc[3][e]);
        acc[3][e] = fmaf(x3.w, w.w, acc[3][e]);
      }
    }
    if (c + 1 < NCH) {  // write staged regs -> next buffer
#pragma unroll
      for (int r = 0; r < 4; ++r) *(float4*)&wbn[wdst[r]] = st[r];
    }
    if (c + 2 < NCH) {  // issue loads for chunk c+2 (hidden under next compute)
#pragma unroll
      for (int r = 0; r < 4; ++r)
        st[r] = *(const float4*)(gws + (size_t)r * 16 * DD + (c + 2) * KC);
    }
    __syncthreads();
  }

  // write partial logits: lgp[kq][tok_local 64][LGSTR] (aliases dead wbufs)
  {
    float* lgp = &smem[kq * LGKQ];
#pragma unroll
    for (int t = 0; t < 4; ++t) {
      float* row = &lgp[(tg * 32 + s + 8 * t) * LGSTR + g * 8];
      float4 a0, a1;
      a0.x = acc[t][0]; a0.y = acc[t][1]; a0.z = acc[t][2]; a0.w = acc[t][3];
      a1.x = acc[t][4]; a1.y = acc[t][5]; a1.z = acc[t][6]; a1.w = acc[t][7];
      *(float4*)&row[0] = a0;
      *(float4*)&row[4] = a1;
    }
  }
  __syncthreads();

  // epilogue: wave wid -> tokens wid*8..wid*8+7; lane == expert
  float psum_local = 0.f, cnt_local = 0.f;
  float* out_v = out;                // (NTOK, 2) top-k vals
  float* out_i = out + NTOK * TOPK;  // (NTOK, 2) top-k idx as float
#pragma unroll 1
  for (int ii = 0; ii < 8; ++ii) {
    const int t = wid * 8 + ii;
    float v = smem[0 * LGKQ + t * LGSTR + lane] +
              smem[1 * LGKQ + t * LGSTR + lane] +
              smem[2 * LGKQ + t * LGSTR + lane] +
              smem[3 * LGKQ + t * LGSTR + lane];
    float m = v;
#pragma unroll
    for (int sh = 32; sh > 0; sh >>= 1) m = fmaxf(m, __shfl_xor(m, sh, 64));
    float ex = expf(v - m);
    float ssum = ex;
#pragma unroll
    for (int sh = 32; sh > 0; sh >>= 1) ssum += __shfl_xor(ssum, sh, 64);
    float p = ex / ssum;
    psum_local += p;

    float v1 = p; int i1 = lane;  // top-1, ties -> lowest index
#pragma unroll
    for (int sh = 32; sh > 0; sh >>= 1) {
      float ov = __shfl_xor(v1, sh, 64);
      int oi = __shfl_xor(i1, sh, 64);
      if (ov > v1 || (ov == v1 && oi < i1)) { v1 = ov; i1 = oi; }
    }
    float v2 = (lane == i1) ? -INFINITY : p; int i2 = lane;  // top-2
#pragma unroll
    for (int sh = 32; sh > 0; sh >>= 1) {
      float ov = __shfl_xor(v2, sh, 64);
      int oi = __shfl_xor(i2, sh, 64);
      if (ov > v2 || (ov == v2 && oi < i2)) { v2 = ov; i2 = oi; }
    }
    cnt_local += (lane == i1 ? 1.f : 0.f) + (lane == i2 ? 1.f : 0.f);
    if (lane == 0) {
      const int tgl = tok0 + t;
      out_v[tgl * 2 + 0] = v1;
      out_v[tgl * 2 + 1] = v2;
      out_i[tgl * 2 + 0] = (float)i1;
      out_i[tgl * 2 + 1] = (float)i2;
    }
  }
  // loss partials: ws[0:64] = pick counts, ws[64:128] = prob sums
  atomicAdd(ws + lane, cnt_local);
  atomicAdd(ws + NE + lane, psum_local);
}

__global__ void loss_kernel(const float* __restrict__ ws,
                            float* __restrict__ out) {
  const int lane = threadIdx.x & 63;
  float f = ws[lane] * (1.f / (float)(NTOK * TOPK));
  float p = ws[NE + lane] * (1.f / (float)NTOK);
  float v = f * p;  // loss = E * mean_i(f_i p_i) = sum_i f_i p_i
#pragma unroll
  for (int sh = 32; sh > 0; sh >>= 1) v += __shfl_xor(v, sh, 64);
  if (lane == 0) out[NTOK * TOPK * 2] = v;
}

extern "C" void kernel_launch(void* const* d_in, const int* in_sizes, int n_in,
                              void* d_out, int out_size, void* d_ws,
                              size_t ws_size, hipStream_t stream) {
  const float* x = (const float*)d_in[0];
  const float* gw = (const float*)d_in[1];
  float* out = (float*)d_out;
  float* ws = (float*)d_ws;

  hipMemsetAsync(d_ws, 0, 2 * NE * sizeof(float), stream);
  router_kernel<<<NTOK / TOKPB, BLOCK, 0, stream>>>(x, gw, out, ws);
  loss_kernel<<<1, 64, 0, stream>>>(ws, out);
}

// Round 6
// 869.525 us; speedup vs baseline: 3.4245x; 1.7472x over previous
//
#include <hip/hip_runtime.h>
#include <math.h>

#define NE 64
#define NTOK 16384
#define DD 4096
#define TOPK 2
#define BLOCK 512            // 8 waves = 2 expert-halves x 4 K-quarters
#define TOKPB 64
#define KQn 4
#define KRANGE (DD / KQn)    // 1024 k per quarter
#define KC 16                // k per chunk (one 64B line per row)
#define NCH (KRANGE / KC)    // 64 chunks
#define WROWS 32             // expert rows per wave (its eg-half)
#define WBUF (WROWS * KC)    // 512 dwords = 2KB per wave
#define LGSTR 68             // logit plane row stride
#define LGKQ (64 * LGSTR)    // 4352 dwords per kq plane
#define SMEM_DW (KQn * LGKQ) // 17408 dwords = 69.6 KB (weights alias first 16KB)

// grid = 256 = exactly 1 block/CU; (512,1) -> 256-VGPR cap, no spill cliff.
__global__ __launch_bounds__(BLOCK, 1) void router_kernel(
    const float* __restrict__ x, const float* __restrict__ gw,
    float* __restrict__ out, float* __restrict__ ws) {
  __shared__ __align__(16) float smem[SMEM_DW];

  const int tid = threadIdx.x;
  const int lane = tid & 63;
  const int wid = __builtin_amdgcn_readfirstlane(tid >> 6);
  const int eg = wid & 1;   // expert half: experts eg*32 .. eg*32+31
  const int kq = wid >> 1;  // K quarter
  const int g = lane >> 3;  // expert sub-row 0..7 (experts eg*32 + g + 8j)
  const int s = lane & 7;   // token slot (tokens s + 8t, t=0..7)
  const int g3 = g & 3;
  const int tok0 = blockIdx.x * TOKPB;

  // per-token x row pointers (8 tokens per lane; dup across g -> coalescer dedup)
  const float* xt[8];
#pragma unroll
  for (int t = 0; t < 8; ++t)
    xt[t] = x + (size_t)(tok0 + s + 8 * t) * DD + kq * KRANGE;

  // weight staging: lane l stages 16B pieces; LDS dest LINEAR (dst = wbase+l*4),
  // source pre-swizzled so read slot (q^g3) of row r holds global quad q.
  const int r0 = lane >> 2;  // 0..15
  const int q1 = lane & 3;
  const int sw = q1 ^ (r0 & 3);
  const float* ws0 = gw + (size_t)(eg * 32 + r0) * DD + kq * KRANGE + sw * 4;
  const float* ws1 = ws0 + (size_t)16 * DD;  // row r0+16 (same swizzle)
  const int wbase = wid * WBUF;
  const int dst0 = wbase + lane * 4;        // linear
  const int dst1 = dst0 + 256;              // +16 rows

  // per-quad swizzled read bases (dwords): row g, slot q^g3; +j*128 for row g+8j
  int wq[4];
#pragma unroll
  for (int q = 0; q < 4; ++q) wq[q] = wbase + g * 16 + ((q ^ g3) << 2);

  float acc[8][4];
#pragma unroll
  for (int t = 0; t < 8; ++t)
#pragma unroll
    for (int j = 0; j < 4; ++j) acc[t][j] = 0.f;

  // prologue: weight chunk 0 in regs; x pair 0 (quads 0,1) in regs
  float4 st0 = *(const float4*)ws0;
  float4 st1 = *(const float4*)ws1;
  float4 pa[8], pb[8], na[8], nb[8];
#pragma unroll
  for (int t = 0; t < 8; ++t) {
    pa[t] = *(const float4*)(xt[t] + 0);
    pb[t] = *(const float4*)(xt[t] + 4);
  }

#define QUAD(QL, XV)                                                     \
  do {                                                                   \
    const float4 w0 = *(const float4*)&smem[wq[QL] + 0 * 128];           \
    const float4 w1 = *(const float4*)&smem[wq[QL] + 1 * 128];           \
    const float4 w2 = *(const float4*)&smem[wq[QL] + 2 * 128];           \
    const float4 w3 = *(const float4*)&smem[wq[QL] + 3 * 128];           \
    _Pragma("unroll") for (int t = 0; t < 8; ++t) {                      \
      const float4 xv = XV[t];                                           \
      acc[t][0] = fmaf(xv.x, w0.x, acc[t][0]);                           \
      acc[t][0] = fmaf(xv.y, w0.y, acc[t][0]);                           \
      acc[t][0] = fmaf(xv.z, w0.z, acc[t][0]);                           \
      acc[t][0] = fmaf(xv.w, w0.w, acc[t][0]);                           \
      acc[t][1] = fmaf(xv.x, w1.x, acc[t][1]);                           \
      acc[t][1] = fmaf(xv.y, w1.y, acc[t][1]);                           \
      acc[t][1] = fmaf(xv.z, w1.z, acc[t][1]);                           \
      acc[t][1] = fmaf(xv.w, w1.w, acc[t][1]);                           \
      acc[t][2] = fmaf(xv.x, w2.x, acc[t][2]);                           \
      acc[t][2] = fmaf(xv.y, w2.y, acc[t][2]);                           \
      acc[t][2] = fmaf(xv.z, w2.z, acc[t][2]);                           \
      acc[t][2] = fmaf(xv.w, w2.w, acc[t][2]);                           \
      acc[t][3] = fmaf(xv.x, w3.x, acc[t][3]);                           \
      acc[t][3] = fmaf(xv.y, w3.y, acc[t][3]);                           \
      acc[t][3] = fmaf(xv.z, w3.z, acc[t][3]);                           \
      acc[t][3] = fmaf(xv.w, w3.w, acc[t][3]);                           \
    }                                                                    \
  } while (0)

#pragma unroll 1
  for (int c = 0; c < NCH; ++c) {
    const int base = c * KC;
    // write chunk c weights to this wave's private buffer (in-order DS:
    // prior chunk's reads retire first; no barrier needed)
    *(float4*)&smem[dst0] = st0;
    *(float4*)&smem[dst1] = st1;
    if (c + 1 < NCH) {  // global loads for chunk c+1 (latency hidden by chunk)
      st0 = *(const float4*)(ws0 + (c + 1) * KC);
      st1 = *(const float4*)(ws1 + (c + 1) * KC);
    }
    // issue x pair1 (quads 2,3) loads, compute pair0 (quads 0,1)
#pragma unroll
    for (int t = 0; t < 8; ++t) {
      na[t] = *(const float4*)(xt[t] + base + 8);
      nb[t] = *(const float4*)(xt[t] + base + 12);
    }
    QUAD(0, pa);
    QUAD(1, pb);
    // issue x pair0 of next chunk, compute pair1
    if (c + 1 < NCH) {
#pragma unroll
      for (int t = 0; t < 8; ++t) {
        pa[t] = *(const float4*)(xt[t] + base + 16);
        pb[t] = *(const float4*)(xt[t] + base + 20);
      }
    }
    QUAD(2, na);
    QUAD(3, nb);
  }
#undef QUAD

  __syncthreads();  // all compute done; weight buffers die, planes alias

  // partial logits: plane[kq][tok 64][LGSTR]; expert col = eg*32 + g + 8j
#pragma unroll
  for (int t = 0; t < 8; ++t) {
    float* row = &smem[kq * LGKQ + (s + 8 * t) * LGSTR + eg * 32 + g];
#pragma unroll
    for (int j = 0; j < 4; ++j) row[8 * j] = acc[t][j];
  }
  __syncthreads();

  // epilogue: wave wid -> tokens wid*8..+7; lane == expert
  float psum_local = 0.f, cnt_local = 0.f;
  float* out_v = out;                // (NTOK, 2) top-k vals
  float* out_i = out + NTOK * TOPK;  // (NTOK, 2) top-k idx as float
#pragma unroll 1
  for (int ii = 0; ii < 8; ++ii) {
    const int t = wid * 8 + ii;
    float v = smem[0 * LGKQ + t * LGSTR + lane] +
              smem[1 * LGKQ + t * LGSTR + lane] +
              smem[2 * LGKQ + t * LGSTR + lane] +
              smem[3 * LGKQ + t * LGSTR + lane];
    float m = v;
#pragma unroll
    for (int sh = 32; sh > 0; sh >>= 1) m = fmaxf(m, __shfl_xor(m, sh, 64));
    float ex = expf(v - m);
    float ssum = ex;
#pragma unroll
    for (int sh = 32; sh > 0; sh >>= 1) ssum += __shfl_xor(ssum, sh, 64);
    float p = ex / ssum;
    psum_local += p;

    float v1 = p; int i1 = lane;  // top-1, ties -> lowest index
#pragma unroll
    for (int sh = 32; sh > 0; sh >>= 1) {
      float ov = __shfl_xor(v1, sh, 64);
      int oi = __shfl_xor(i1, sh, 64);
      if (ov > v1 || (ov == v1 && oi < i1)) { v1 = ov; i1 = oi; }
    }
    float v2 = (lane == i1) ? -INFINITY : p; int i2 = lane;  // top-2
#pragma unroll
    for (int sh = 32; sh > 0; sh >>= 1) {
      float ov = __shfl_xor(v2, sh, 64);
      int oi = __shfl_xor(i2, sh, 64);
      if (ov > v2 || (ov == v2 && oi < i2)) { v2 = ov; i2 = oi; }
    }
    cnt_local += (lane == i1 ? 1.f : 0.f) + (lane == i2 ? 1.f : 0.f);
    if (lane == 0) {
      const int tg = tok0 + t;
      out_v[tg * 2 + 0] = v1;
      out_v[tg * 2 + 1] = v2;
      out_i[tg * 2 + 0] = (float)i1;
      out_i[tg * 2 + 1] = (float)i2;
    }
  }
  // loss partials: ws[0:64] = pick counts, ws[64:128] = prob sums
  atomicAdd(ws + lane, cnt_local);
  atomicAdd(ws + NE + lane, psum_local);
}

__global__ void loss_kernel(const float* __restrict__ ws,
                            float* __restrict__ out) {
  const int lane = threadIdx.x & 63;
  float f = ws[lane] * (1.f / (float)(NTOK * TOPK));
  float p = ws[NE + lane] * (1.f / (float)NTOK);
  float v = f * p;  // loss = E * mean_i(f_i p_i) = sum_i f_i p_i
#pragma unroll
  for (int sh = 32; sh > 0; sh >>= 1) v += __shfl_xor(v, sh, 64);
  if (lane == 0) out[NTOK * TOPK * 2] = v;
}

extern "C" void kernel_launch(void* const* d_in, const int* in_sizes, int n_in,
                              void* d_out, int out_size, void* d_ws,
                              size_t ws_size, hipStream_t stream) {
  const float* x = (const float*)d_in[0];
  const float* gw = (const float*)d_in[1];
  float* out = (float*)d_out;
  float* ws = (float*)d_ws;

  hipMemsetAsync(d_ws, 0, 2 * NE * sizeof(float), stream);
  router_kernel<<<NTOK / TOKPB, BLOCK, 0, stream>>>(x, gw, out, ws);
  loss_kernel<<<1, 64, 0, stream>>>(ws, out);
}